// Round 1
// baseline (715.161 us; speedup 1.0000x reference)
//
#include <hip/hip_runtime.h>

// Problem constants (from reference): N=100000 nodes, E=3000000 edges,
// G=256 graphs, F_IN=64, NHID=32. Derived at launch from in_sizes where easy.

#define BLK 256

// K0: init ew=1 (fallback; masks actually cover all E), deg=1 (self-loop),
//     thread 0 computes softmax(msg_weights) -> sp[3]
__global__ void k0_init(float* __restrict__ ew, float* __restrict__ deg,
                        float* __restrict__ sp, const float* __restrict__ mw,
                        int n_edges, int n_nodes) {
    int i = blockIdx.x * blockDim.x + threadIdx.x;
    if (i < n_edges) ew[i] = 1.0f;
    if (i < n_nodes) deg[i] = 1.0f;
    if (i == 0) {
        float a = mw[0], b = mw[1], c = mw[2];
        float m = fmaxf(a, fmaxf(b, c));
        float ea = expf(a - m), eb = expf(b - m), ec = expf(c - m);
        float s = ea + eb + ec;
        sp[0] = ea / s; sp[1] = eb / s; sp[2] = ec / s;
    }
}

// K1: scatter edge weights from the three masks + accumulate degree at col.
// Masks are a permutation split -> each edge set exactly once.
__global__ void k1_scatter_deg(const int* __restrict__ km, const int* __restrict__ um,
                               const int* __restrict__ om, int s0, int s1, int s2,
                               const int* __restrict__ col, const float* __restrict__ sp,
                               float* __restrict__ ew, float* __restrict__ deg) {
    int i = blockIdx.x * blockDim.x + threadIdx.x;
    int total = s0 + s1 + s2;
    if (i >= total) return;
    int e; float w;
    if (i < s0)            { e = km[i];            w = sp[0]; }
    else if (i < s0 + s1)  { e = um[i - s0];       w = sp[1]; }
    else                   { e = om[i - s0 - s1];  w = sp[2]; }
    ew[e] = w;
    atomicAdd(&deg[col[e]], w);
}

// K2: deg -> dinv in place
__global__ void k2_dinv(float* __restrict__ deg, int n_nodes) {
    int i = blockIdx.x * blockDim.x + threadIdx.x;
    if (i < n_nodes) {
        float d = deg[i];
        deg[i] = (d > 0.0f) ? rsqrtf(d) : 0.0f;
    }
}

// K3: fold emb_W/emb_b through gcn_W:
//   Wfull[0,j]   = gcn_W[0,j]
//   Wfull[1+m,j] = sum_t emb_W[m,t] * gcn_W[1+t,j]   (m,t in [0,63), j in [0,32))
//   hWbias[j]    = sum_t emb_b[t]   * gcn_W[1+t,j]
__global__ void k3_weights(const float* __restrict__ emb_W, const float* __restrict__ emb_b,
                           const float* __restrict__ gcn_W,
                           float* __restrict__ Wfull, float* __restrict__ hWbias) {
    int t = threadIdx.x;
    for (int idx = t; idx < 64 * 32; idx += blockDim.x) {
        int k = idx >> 5, j = idx & 31;
        float acc;
        if (k == 0) {
            acc = gcn_W[j];
        } else {
            int m = k - 1;
            acc = 0.0f;
            for (int tt = 0; tt < 63; ++tt)
                acc += emb_W[m * 63 + tt] * gcn_W[(1 + tt) * 32 + j];
        }
        Wfull[idx] = acc;
    }
    if (t < 32) {
        float acc = 0.0f;
        for (int tt = 0; tt < 63; ++tt)
            acc += emb_b[tt] * gcn_W[(1 + tt) * 32 + t];
        hWbias[t] = acc;
    }
}

// K4: hW = x @ Wfull + hWbias   (N x 64) @ (64 x 32)
// 8 rows per 256-thread block; W and x rows staged in LDS.
__global__ void k4_gemm(const float* __restrict__ x, const float* __restrict__ Wfull,
                        const float* __restrict__ hWbias, float* __restrict__ hW,
                        int n_nodes) {
    __shared__ float Wl[64 * 32];
    __shared__ float xs[8 * 64];
    int tid = threadIdx.x;
    for (int idx = tid; idx < 2048; idx += BLK) Wl[idx] = Wfull[idx];
    int rowBase = blockIdx.x * 8;
    for (int idx = tid; idx < 512; idx += BLK) {
        int r = rowBase + (idx >> 6);
        xs[idx] = (r < n_nodes) ? x[(size_t)r * 64 + (idx & 63)] : 0.0f;
    }
    __syncthreads();
    int j = tid & 31, lr = tid >> 5;
    int n = rowBase + lr;
    if (n < n_nodes) {
        float acc = hWbias[j];
#pragma unroll
        for (int k = 0; k < 64; ++k)
            acc += xs[lr * 64 + k] * Wl[k * 32 + j];
        hW[(size_t)n * 32 + j] = acc;
    }
}

// K5: edge aggregation. 32 lanes per edge: lane j handles feature j.
//   agg[col, j] += dinv[row]*ew*dinv[col] * hW[row, j]
__global__ void k5_edges(const int* __restrict__ row, const int* __restrict__ col,
                         const float* __restrict__ ew, const float* __restrict__ dinv,
                         const float* __restrict__ hW, float* __restrict__ agg,
                         int n_edges) {
    int t = blockIdx.x * blockDim.x + threadIdx.x;
    int lane = t & 31;
    int e = t >> 5;
    if (e >= n_edges) return;
    int r = row[e], c = col[e];
    float nrm = dinv[r] * ew[e] * dinv[c];
    atomicAdd(&agg[(size_t)c * 32 + lane], nrm * hW[(size_t)r * 32 + lane]);
}

// K6: self-loop + gcn bias + relu + graph pooling (atomic into pooled[G,32])
__global__ void k6_pool(const float* __restrict__ agg, const float* __restrict__ dinv,
                        const float* __restrict__ hW, const float* __restrict__ gcn_b,
                        const int* __restrict__ batch, float* __restrict__ pooled,
                        int n_nodes) {
    int t = blockIdx.x * blockDim.x + threadIdx.x;
    if (t >= n_nodes * 32) return;
    int n = t >> 5, j = t & 31;
    float di = dinv[n];
    float a = agg[t] + di * di * hW[t] + gcn_b[j];
    float hg = fmaxf(a, 0.0f);
    atomicAdd(&pooled[batch[n] * 32 + j], hg);
}

// K7: head: z = relu(pooled @ fc1_W + fc1_b); out = z @ out_W + out_b
__global__ void k7_head(const float* __restrict__ pooled, const float* __restrict__ fc1_W,
                        const float* __restrict__ fc1_b, const float* __restrict__ out_W,
                        const float* __restrict__ out_b, float* __restrict__ out,
                        int n_graphs) {
    __shared__ float Wl[32 * 32];
    __shared__ float bl[32];
    __shared__ float owl[32];
    int t = threadIdx.x;
    for (int idx = t; idx < 1024; idx += BLK) Wl[idx] = fc1_W[idx];
    if (t < 32) { bl[t] = fc1_b[t]; owl[t] = out_W[t]; }
    __syncthreads();
    if (t < n_graphs) {
        float p[32];
#pragma unroll
        for (int k = 0; k < 32; ++k) p[k] = pooled[t * 32 + k];
        float acc = 0.0f;
        for (int j = 0; j < 32; ++j) {
            float z = bl[j];
#pragma unroll
            for (int k = 0; k < 32; ++k) z += p[k] * Wl[k * 32 + j];
            z = fmaxf(z, 0.0f);
            acc += z * owl[j];
        }
        out[t] = acc + out_b[0];
    }
}

extern "C" void kernel_launch(void* const* d_in, const int* in_sizes, int n_in,
                              void* d_out, int out_size, void* d_ws, size_t ws_size,
                              hipStream_t stream) {
    const float* x       = (const float*)d_in[0];
    const int*   ei      = (const int*)d_in[1];
    const int*   batch   = (const int*)d_in[2];
    const int*   km      = (const int*)d_in[3];
    const int*   um      = (const int*)d_in[4];
    const int*   om      = (const int*)d_in[5];
    const float* mw      = (const float*)d_in[6];
    const float* emb_W   = (const float*)d_in[7];
    const float* emb_b   = (const float*)d_in[8];
    const float* gcn_W   = (const float*)d_in[9];
    const float* gcn_b   = (const float*)d_in[10];
    const float* fc1_W   = (const float*)d_in[11];
    const float* fc1_b   = (const float*)d_in[12];
    const float* out_W   = (const float*)d_in[13];
    const float* out_b   = (const float*)d_in[14];

    const int n_nodes = in_sizes[0] / 64;
    const int n_edges = in_sizes[1] / 2;
    const int s0 = in_sizes[3], s1 = in_sizes[4], s2 = in_sizes[5];
    const int n_graphs = out_size;  // 256

    const int* row = ei;
    const int* col = ei + n_edges;

    // Workspace layout (floats):
    float* ws     = (float*)d_ws;
    float* ew     = ws;                       // n_edges
    float* deg    = ew + n_edges;             // n_nodes (becomes dinv in-place)
    float* hW     = deg + n_nodes;            // 32*n_nodes
    float* agg    = hW + (size_t)32 * n_nodes;    // 32*n_nodes  } contiguous
    float* pooled = agg + (size_t)32 * n_nodes;   // 32*n_graphs } zeroed together
    float* Wfull  = pooled + 32 * n_graphs;   // 2048
    float* hWbias = Wfull + 2048;             // 32
    float* sp     = hWbias + 32;              // 3 (+pad)

    // zero agg + pooled in one stream-ordered memset (graph-capturable)
    hipMemsetAsync(agg, 0, ((size_t)32 * n_nodes + 32 * n_graphs) * sizeof(float), stream);

    k0_init<<<(n_edges + BLK - 1) / BLK, BLK, 0, stream>>>(ew, deg, sp, mw, n_edges, n_nodes);
    k1_scatter_deg<<<(s0 + s1 + s2 + BLK - 1) / BLK, BLK, 0, stream>>>(
        km, um, om, s0, s1, s2, col, sp, ew, deg);
    k2_dinv<<<(n_nodes + BLK - 1) / BLK, BLK, 0, stream>>>(deg, n_nodes);
    k3_weights<<<1, BLK, 0, stream>>>(emb_W, emb_b, gcn_W, Wfull, hWbias);
    k4_gemm<<<(n_nodes + 7) / 8, BLK, 0, stream>>>(x, Wfull, hWbias, hW, n_nodes);

    int edge_threads = n_edges * 32;  // 96M, fits int
    k5_edges<<<(edge_threads + BLK - 1) / BLK, BLK, 0, stream>>>(
        row, col, ew, deg, hW, agg, n_edges);

    int node_threads = n_nodes * 32;  // 3.2M
    k6_pool<<<(node_threads + BLK - 1) / BLK, BLK, 0, stream>>>(
        agg, deg, hW, gcn_b, batch, pooled, n_nodes);

    k7_head<<<1, BLK, 0, stream>>>(pooled, fc1_W, fc1_b, out_W, out_b, (float*)d_out, n_graphs);
}